// Round 7
// baseline (402.726 us; speedup 1.0000x reference)
//
#include <hip/hip_runtime.h>
#include <hip/hip_cooperative_groups.h>
#include <math.h>

// SALAD head. Round 7: Sinkhorn -> ONE cooperative kernel, M resident in LDS
// (64 blocks x 128 KB halves), 5 grid syncs. 5 dispatches total.

#define BATCH 32
#define NTOK  1025
#define DIM   768
#define KDIM  64
#define CDIM  128
#define TDIM  256
#define NM1   1024
#define ROWLEN 8448          // TDIM + KDIM*CDIM
#define NITER 5
#define INV_REG 10.0f        // 1/0.1
#define NS_AGG 8             // n-slices in aggregation (128 tokens each)
#define LOG_A (-4.17438727f) // -log(65)
#define LOG_B (-6.93147181f) // -log(1024)

typedef __attribute__((ext_vector_type(8))) short short8;
typedef __attribute__((ext_vector_type(4))) float floatx4;

typedef __attribute__((address_space(3))) unsigned int lds_uint;
typedef const __attribute__((address_space(1))) unsigned int glb_uint;

__device__ __forceinline__ void gload_lds16(const void* g, void* l) {
    __builtin_amdgcn_global_load_lds((glb_uint*)g, (lds_uint*)l, 16, 0, 0);
}

__device__ __forceinline__ unsigned short bf16_rne(float f) {
    unsigned u = __builtin_bit_cast(unsigned, f);
    unsigned r = u + 0x7FFFu + ((u >> 16) & 1u);
    return (unsigned short)(r >> 16);
}

__device__ __forceinline__ short8 cvt8(float4 a, float4 b) {
    short8 r;
    r[0] = (short)bf16_rne(a.x); r[1] = (short)bf16_rne(a.y);
    r[2] = (short)bf16_rne(a.z); r[3] = (short)bf16_rne(a.w);
    r[4] = (short)bf16_rne(b.x); r[5] = (short)bf16_rne(b.y);
    r[6] = (short)bf16_rne(b.z); r[7] = (short)bf16_rne(b.w);
    return r;
}

// ---------------- prep: pack W (blocks 0..575) + t-GEMM (blocks 576..671) --
__global__ __launch_bounds__(256) void prep(
    const float* __restrict__ Wf, const float* __restrict__ Ws,
    const float* __restrict__ bf, const float* __restrict__ bs,
    const float* __restrict__ x, const float* __restrict__ Wt,
    short* __restrict__ W_pack, float* __restrict__ bias_all,
    float* __restrict__ tpart)
{
    __shared__ float xr[256];
    const int blk = blockIdx.x, tid = threadIdx.x;
    if (blk < 576) {
        int idx = blk * 256 + tid;   // < 147456 exactly
        int g    = idx / 6144;
        int rem  = idx - g * 6144;
        int nf   = rem >> 9;
        int rem2 = rem & 511;
        int lane = rem2 >> 3;
        int j    = rem2 & 7;
        int k = g * 32 + (lane >> 4) * 8 + j;
        int c = nf * 16 + (lane & 15);
        float v = (c < CDIM) ? Wf[(size_t)k * CDIM + c] : Ws[(size_t)k * KDIM + (c - CDIM)];
        W_pack[idx] = (short)bf16_rne(v);
        if (idx < 192) bias_all[idx] = (idx < CDIM) ? bf[idx] : bs[idx - CDIM];
    } else {
        int i = blk - 576;           // 0..95
        int b = i / 3, dy = i - b * 3;
        xr[tid] = x[(size_t)b * NTOK * DIM + (size_t)dy * 256 + tid];
        __syncthreads();
        float acc = 0.f;
        const float* wp = Wt + (size_t)dy * 256 * TDIM + tid;
#pragma unroll 8
        for (int d = 0; d < 256; ++d) acc = fmaf(xr[d], wp[(size_t)d * TDIM], acc);
        tpart[((size_t)dy * BATCH + b) * TDIM + tid] = acc;
    }
}

// ---------------- fused f / s GEMM via MFMA + LDS staging ----------------
__global__ __launch_bounds__(256, 2) void gemm_fs(
    const float* __restrict__ x, const short* __restrict__ W_pack,
    const float* __restrict__ bias_all, const float* __restrict__ sharp_p,
    unsigned short* __restrict__ fT, float* __restrict__ Mmat)
{
    __shared__ __align__(16) short Bs[12288];  // 24 KB  [kk][nf][lane][8]
    __shared__ __align__(16) short As[4096];   //  8 KB  [wave][kk][lane][8]
    const int tid  = threadIdx.x;
    const int wave = tid >> 6, lane = tid & 63;
    const int quad = lane >> 4, lrow = lane & 15;
    const int R = blockIdx.x * 64 + wave * 16;

    const int arow = blockIdx.x * 64 + (tid >> 2);
    const float* asrc = x + ((size_t)(arow >> 10) * NTOK + 1 + (arow & 1023)) * DIM + (tid & 3) * 16;
    const int r    = (tid >> 2) & 15;
    const int seg  = tid & 3;
    const int kk_w = seg >> 1;
    const int q0   = (seg & 1) * 2;
    short* adst0 = &As[(((tid >> 6) * 2 + kk_w) * 64 + q0 * 16 + r) * 8];
    short* adst1 = &As[(((tid >> 6) * 2 + kk_w) * 64 + (q0 + 1) * 16 + r) * 8];

    floatx4 acc[12];
#pragma unroll
    for (int nf = 0; nf < 12; ++nf) acc[nf] = (floatx4){0.f, 0.f, 0.f, 0.f};

    float4 g0 = *(const float4*)(asrc);
    float4 g1 = *(const float4*)(asrc + 4);
    float4 g2 = *(const float4*)(asrc + 8);
    float4 g3 = *(const float4*)(asrc + 12);

    for (int ko = 0; ko < 12; ++ko) {
        __syncthreads();
        const short* bsrc = W_pack + ko * 12288 + tid * 8;
#pragma unroll
        for (int i = 0; i < 6; ++i)
            gload_lds16(bsrc + i * 2048, &Bs[i * 2048 + tid * 8]);
        *(short8*)adst0 = cvt8(g0, g1);
        *(short8*)adst1 = cvt8(g2, g3);
        if (ko < 11) {
            const float* ap = asrc + (ko + 1) * 64;
            g0 = *(const float4*)(ap);
            g1 = *(const float4*)(ap + 4);
            g2 = *(const float4*)(ap + 8);
            g3 = *(const float4*)(ap + 12);
        }
        __syncthreads();
#pragma unroll
        for (int kk = 0; kk < 2; ++kk) {
            short8 af = *(const short8*)&As[((wave * 2 + kk) * 64 + lane) * 8];
#pragma unroll
            for (int nf = 0; nf < 12; ++nf) {
                short8 bf8 = *(const short8*)&Bs[((kk * 12 + nf) * 64 + lane) * 8];
                acc[nf] = __builtin_amdgcn_mfma_f32_16x16x32_bf16(af, bf8, acc[nf], 0, 0, 0);
            }
        }
    }

    const float sc = sharp_p[0] * INV_REG;
    const int bb = R >> 10;
    const int tok = (R & 1023) + quad * 4;
#pragma unroll
    for (int nf = 0; nf < 12; ++nf) {
        const int c = nf * 16 + lrow;
        const float bias = bias_all[c];
        if (nf < 8) {
            ushort4 w;
            w.x = bf16_rne(acc[nf][0] + bias);
            w.y = bf16_rne(acc[nf][1] + bias);
            w.z = bf16_rne(acc[nf][2] + bias);
            w.w = bf16_rne(acc[nf][3] + bias);
            *(ushort4*)(fT + ((size_t)bb * CDIM + c) * NM1 + tok) = w;
        } else {
            const int k = c - CDIM;
            float4 w = make_float4((acc[nf][0] + bias) * sc, (acc[nf][1] + bias) * sc,
                                   (acc[nf][2] + bias) * sc, (acc[nf][3] + bias) * sc);
            *(float4*)(Mmat + ((size_t)bb * KDIM + k) * NM1 + tok) = w;
        }
    }
}

// ---------------- cooperative Sinkhorn: M in LDS, 5 grid syncs -------------
// 64 blocks x 1024 thr; block (b,h) owns M[b][all 64 k][h*512 .. h*512+511]
// in 128 KB dynamic LDS. v-update fully local; u-update via 65 (max,S)
// partials merged across the 2 halves (ping-pong buffers + grid.sync).
__device__ __forceinline__ void u_partial(
    const float* Msh, const float* vs, float* upp, int blk,
    int wave, int lane, float dustM, bool use_v)
{
#pragma unroll
    for (int r = 0; r < 4; ++r) {
        const int k = wave * 4 + r;
        float loc[8];
        float m = -INFINITY;
#pragma unroll
        for (int i = 0; i < 8; ++i) {
            float xv = Msh[k * 512 + i * 64 + lane] + (use_v ? vs[i * 64 + lane] : 0.f);
            loc[i] = xv;
            m = fmaxf(m, xv);
        }
#pragma unroll
        for (int off = 1; off < 64; off <<= 1) m = fmaxf(m, __shfl_xor(m, off));
        float S = 0.f;
#pragma unroll
        for (int i = 0; i < 8; ++i) S += __expf(loc[i] - m);
#pragma unroll
        for (int off = 1; off < 64; off <<= 1) S += __shfl_xor(S, off);
        if (lane == 0) {
            upp[(blk * 65 + k) * 2]     = m;
            upp[(blk * 65 + k) * 2 + 1] = S;
        }
    }
    if (wave == 0) {            // implicit dust row: dustM + v_n
        float m, S;
        if (use_v) {
            float loc[8];
            float vm = -INFINITY;
#pragma unroll
            for (int i = 0; i < 8; ++i) { loc[i] = vs[i * 64 + lane]; vm = fmaxf(vm, loc[i]); }
#pragma unroll
            for (int off = 1; off < 64; off <<= 1) vm = fmaxf(vm, __shfl_xor(vm, off));
            float s = 0.f;
#pragma unroll
            for (int i = 0; i < 8; ++i) s += __expf(loc[i] - vm);
#pragma unroll
            for (int off = 1; off < 64; off <<= 1) s += __shfl_xor(s, off);
            m = dustM + vm; S = s;
        } else {
            m = dustM; S = 512.f;
        }
        if (lane == 0) {
            upp[(blk * 65 + 64) * 2]     = m;
            upp[(blk * 65 + 64) * 2 + 1] = S;
        }
    }
}

__global__ __launch_bounds__(1024) void sink_coop(
    const float* __restrict__ Mmat, const float* __restrict__ dust_p,
    float* __restrict__ u_buf, float* __restrict__ v_buf,
    float* __restrict__ up)    // up[2][64][65][2]
{
    extern __shared__ float Msh[];    // 64 x 512 fp32 = 128 KB
    __shared__ float us[65];
    __shared__ float vs[512];
    cooperative_groups::grid_group grid = cooperative_groups::this_grid();
    const int blk = blockIdx.x, b = blk >> 1, h = blk & 1;
    const int tid = threadIdx.x, wave = tid >> 6, lane = tid & 63;
    const float dustM = dust_p[0] * INV_REG;

    // load this half of M (coalesced float4)
    {
        const float4* src = (const float4*)(Mmat + (size_t)b * KDIM * NM1 + h * 512);
        float4* dst = (float4*)Msh;
#pragma unroll
        for (int q = 0; q < 8; ++q) {
            int idx = q * 1024 + tid;        // 8192 float4
            int k = idx >> 7, j4 = idx & 127;
            dst[k * 128 + j4] = src[(size_t)k * 256 + j4];
        }
    }
    __syncthreads();

    u_partial(Msh, vs, up, blk, wave, lane, dustM, false);
    __threadfence();
    grid.sync();

    for (int it = 0; it < NITER; ++it) {
        // merge the two halves' partials -> u
        const float* rd = up + (it & 1) * (64 * 65 * 2);
        if (tid < 65) {
            const int peer = blk ^ 1;
            float m0 = rd[(blk * 65 + tid) * 2],  S0 = rd[(blk * 65 + tid) * 2 + 1];
            float m1 = rd[(peer * 65 + tid) * 2], S1 = rd[(peer * 65 + tid) * 2 + 1];
            float mm = fmaxf(m0, m1);
            float S = S0 * __expf(m0 - mm) + S1 * __expf(m1 - mm);
            us[tid] = LOG_A - (mm + __logf(S));
        }
        __syncthreads();
        // v-update: fully local (block owns all 64 k for its columns)
        if (tid < 512) {
            float xs[64];
#pragma unroll
            for (int k = 0; k < 64; ++k) xs[k] = Msh[k * 512 + tid] + us[k];
            const float xd = dustM + us[64];
            float m = xd;
#pragma unroll
            for (int k = 0; k < 64; ++k) m = fmaxf(m, xs[k]);
            float S = __expf(xd - m);
#pragma unroll
            for (int k = 0; k < 64; ++k) S += __expf(xs[k] - m);
            vs[tid] = LOG_B - (m + __logf(S));
        }
        __syncthreads();
        if (it < NITER - 1) {
            u_partial(Msh, vs, up + ((it + 1) & 1) * (64 * 65 * 2), blk, wave, lane, dustM, true);
            __threadfence();
            grid.sync();
        } else {
            if (h == 0 && tid < 65) u_buf[b * 65 + tid] = us[tid];
            if (tid < 512) v_buf[(size_t)b * NM1 + h * 512 + tid] = vs[tid];
        }
    }
}

// ---------------- aggregation via MFMA ----------------
__global__ __launch_bounds__(256) void aggregate(
    const float* __restrict__ Mmat, const unsigned short* __restrict__ fT,
    const float* __restrict__ u_in, const float* __restrict__ v_in,
    float* __restrict__ vpart, float* __restrict__ rspart)
{
    __shared__ float us[KDIM];
    __shared__ float vsh[128];
    const int b = blockIdx.x, ns = blockIdx.y;
    const int tid = threadIdx.x;
    const int wave = tid >> 6, lane = tid & 63;
    const int quad = lane >> 4, lrow = lane & 15;

    if (tid < 64) us[tid] = u_in[b * 65 + tid];
    else if (tid < 192) vsh[tid - 64] = v_in[(size_t)b * NM1 + ns * 128 + (tid - 64)];
    __syncthreads();

    const int krow = wave * 16 + lrow;
    const float uk = us[krow];
    const float* Mrow = Mmat + ((size_t)b * KDIM + krow) * NM1 + ns * 128 + quad * 8;
    const unsigned short* fbase = fT + ((size_t)b * CDIM + lrow) * NM1 + ns * 128 + quad * 8;

    floatx4 acc[8];
#pragma unroll
    for (int nf = 0; nf < 8; ++nf) acc[nf] = (floatx4){0.f, 0.f, 0.f, 0.f};
    float rs = 0.f;

#pragma unroll
    for (int step = 0; step < 4; ++step) {
        const float* mp = Mrow + step * 32;
        float4 m0 = *(const float4*)(mp);
        float4 m1 = *(const float4*)(mp + 4);
        const int tb = step * 32 + quad * 8;
        float p[8];
        p[0] = __expf(m0.x + uk + vsh[tb + 0]);
        p[1] = __expf(m0.y + uk + vsh[tb + 1]);
        p[2] = __expf(m0.z + uk + vsh[tb + 2]);
        p[3] = __expf(m0.w + uk + vsh[tb + 3]);
        p[4] = __expf(m1.x + uk + vsh[tb + 4]);
        p[5] = __expf(m1.y + uk + vsh[tb + 5]);
        p[6] = __expf(m1.z + uk + vsh[tb + 6]);
        p[7] = __expf(m1.w + uk + vsh[tb + 7]);
        short8 afrag;
#pragma unroll
        for (int j = 0; j < 8; ++j) {
            rs += p[j];
            afrag[j] = (short)bf16_rne(p[j]);
        }
#pragma unroll
        for (int nf = 0; nf < 8; ++nf) {
            short8 bfrag = *(const short8*)(fbase + (size_t)nf * 16 * NM1 + step * 32);
            acc[nf] = __builtin_amdgcn_mfma_f32_16x16x32_bf16(afrag, bfrag, acc[nf], 0, 0, 0);
        }
    }

    rs += __shfl_xor(rs, 16);
    rs += __shfl_xor(rs, 32);
    if (lane < 16) rspart[(ns * BATCH + b) * KDIM + krow] = rs;

    float* vp = vpart + (size_t)(ns * BATCH + b) * (KDIM * CDIM);
#pragma unroll
    for (int nf = 0; nf < 8; ++nf) {
        const int c = nf * 16 + lrow;
#pragma unroll
        for (int j = 0; j < 4; ++j)
            vp[(size_t)(wave * 16 + quad * 4 + j) * CDIM + c] = acc[nf][j];
    }
}

// ---------------- finalize: reduce partials, anchors, L2-normalize ---------
__global__ __launch_bounds__(1024) void finalize_all(
    const float* __restrict__ vpart, const float* __restrict__ rspart,
    const float* __restrict__ anchors, const float* __restrict__ tpart,
    const float* __restrict__ bt, float* __restrict__ out)
{
    __shared__ float rstot[KDIM];
    __shared__ float red[16];
    __shared__ float sc_sh;
    const int b = blockIdx.x, tid = threadIdx.x;
    const int lane = tid & 63, wave = tid >> 6;

    if (tid < KDIM) {
        float s = 0.f;
#pragma unroll
        for (int ns = 0; ns < NS_AGG; ++ns)
            s += rspart[(ns * BATCH + b) * KDIM + tid];
        rstot[tid] = s;
    }
    __syncthreads();

    const size_t e0 = (size_t)tid * 8;
    float4 s0 = make_float4(0.f, 0.f, 0.f, 0.f);
    float4 s1 = make_float4(0.f, 0.f, 0.f, 0.f);
#pragma unroll
    for (int ns = 0; ns < NS_AGG; ++ns) {
        const float* vp = vpart + (size_t)(ns * BATCH + b) * (KDIM * CDIM) + e0;
        float4 a = *(const float4*)(vp);
        float4 c = *(const float4*)(vp + 4);
        s0.x += a.x; s0.y += a.y; s0.z += a.z; s0.w += a.w;
        s1.x += c.x; s1.y += c.y; s1.z += c.z; s1.w += c.w;
    }
    const float rsv = rstot[tid >> 4];
    float4 a0 = *(const float4*)(anchors + e0);
    float4 a1 = *(const float4*)(anchors + e0 + 4);
    float4 v0, v1;
    v0.x = 2.f * s0.x - rsv * a0.x;  v0.y = 2.f * s0.y - rsv * a0.y;
    v0.z = 2.f * s0.z - rsv * a0.z;  v0.w = 2.f * s0.w - rsv * a0.w;
    v1.x = 2.f * s1.x - rsv * a1.x;  v1.y = 2.f * s1.y - rsv * a1.y;
    v1.z = 2.f * s1.z - rsv * a1.z;  v1.w = 2.f * s1.w - rsv * a1.w;
    float ss = v0.x*v0.x + v0.y*v0.y + v0.z*v0.z + v0.w*v0.w
             + v1.x*v1.x + v1.y*v1.y + v1.z*v1.z + v1.w*v1.w;

    float t = 0.f;
    if (tid < TDIM) {
        t = bt[tid];
#pragma unroll
        for (int s = 0; s < 3; ++s) t += tpart[((size_t)s * BATCH + b) * TDIM + tid];
        ss += t * t;
    }

#pragma unroll
    for (int off = 32; off > 0; off >>= 1) ss += __shfl_down(ss, off);
    if (lane == 0) red[wave] = ss;
    __syncthreads();
    if (tid == 0) {
        float tot = 0.f;
#pragma unroll
        for (int i = 0; i < 16; ++i) tot += red[i];
        sc_sh = 1.f / fmaxf(sqrtf(tot), 1e-12f);
    }
    __syncthreads();
    const float scale = sc_sh;

    float* orow = out + (size_t)b * ROWLEN;
    if (tid < TDIM) orow[tid] = t * scale;
    v0.x *= scale; v0.y *= scale; v0.z *= scale; v0.w *= scale;
    v1.x *= scale; v1.y *= scale; v1.z *= scale; v1.w *= scale;
    *(float4*)&orow[TDIM + e0]     = v0;
    *(float4*)&orow[TDIM + e0 + 4] = v1;
}

// ---------------- launcher ----------------
extern "C" void kernel_launch(void* const* d_in, const int* in_sizes, int n_in,
                              void* d_out, int out_size, void* d_ws, size_t ws_size,
                              hipStream_t stream)
{
    const float* x       = (const float*)d_in[0];
    const float* Wf      = (const float*)d_in[1];
    const float* bf      = (const float*)d_in[2];
    const float* Ws      = (const float*)d_in[3];
    const float* bs      = (const float*)d_in[4];
    const float* Wt      = (const float*)d_in[5];
    const float* bt      = (const float*)d_in[6];
    const float* anchors = (const float*)d_in[7];
    const float* dust    = (const float*)d_in[8];
    const float* sharp   = (const float*)d_in[9];
    float* out = (float*)d_out;

    char* base = (char*)d_ws;
    short* W_pack        = (short*)base;                       // 294912 B
    float* bias_all      = (float*)(base + 294912);            // 192 fl
    float* Mmat          = bias_all + 192;                     // 2097152 fl
    unsigned short* fT   = (unsigned short*)(Mmat + (size_t)BATCH * KDIM * NM1); // 4194304 us
    float* u_buf         = (float*)(fT + (size_t)BATCH * CDIM * NM1);  // 2080 fl
    float* v_buf         = u_buf + BATCH * 65;                 // 32768 fl
    float* vpart         = v_buf + BATCH * NM1;                // 2097152 fl
    float* rspart        = vpart + (size_t)NS_AGG * BATCH * KDIM * CDIM; // 16384 fl
    float* tpart         = rspart + NS_AGG * BATCH * KDIM;     // 24576 fl
    float* up            = tpart + 3 * BATCH * TDIM;           // 2*64*65*2 fl

    hipLaunchKernelGGL(prep, dim3(672), dim3(256), 0, stream,
                       Wf, Ws, bf, bs, x, Wt, W_pack, bias_all, tpart);
    hipLaunchKernelGGL(gemm_fs, dim3(512), dim3(256), 0, stream,
                       x, W_pack, bias_all, sharp, fT, Mmat);

    // cooperative Sinkhorn: 64 blocks x 1024 thr, 128 KB dynamic LDS
    {
        static bool attr_set = false;   // idempotent host-side attr (not stream work)
        if (!attr_set) {
            hipFuncSetAttribute(reinterpret_cast<const void*>(sink_coop),
                                hipFuncAttributeMaxDynamicSharedMemorySize, 131072);
            attr_set = true;
        }
        const float* Mc = Mmat; const float* dc = dust;
        float* ub = u_buf; float* vb = v_buf; float* upp = up;
        void* args[] = { (void*)&Mc, (void*)&dc, (void*)&ub, (void*)&vb, (void*)&upp };
        hipLaunchCooperativeKernel(reinterpret_cast<void*>(sink_coop),
                                   dim3(64), dim3(1024), args, 131072, stream);
    }

    hipLaunchKernelGGL(aggregate, dim3(BATCH, NS_AGG), dim3(256), 0, stream,
                       Mmat, fT, u_buf, v_buf, vpart, rspart);
    hipLaunchKernelGGL(finalize_all, dim3(BATCH), dim3(1024), 0, stream,
                       vpart, rspart, anchors, tpart, bt, out);
}

// Round 8
// 261.668 us; speedup vs baseline: 1.5391x; 1.5391x over previous
//
#include <hip/hip_runtime.h>
#include <math.h>

// SALAD head. Round 8: revert coop (grid.sync ≈ 33 µs each on gfx950 — dead
// end). Sinkhorn iterations flow through dispatch boundaries: sink_step does
// {merge u-partials -> v-update -> next u-partials} per 128-col slice with M
// in LDS; last step fuses the MFMA aggregation. 9 dispatches.

#define BATCH 32
#define NTOK  1025
#define DIM   768
#define KDIM  64
#define CDIM  128
#define TDIM  256
#define NM1   1024
#define ROWLEN 8448          // TDIM + KDIM*CDIM
#define NITER 5
#define INV_REG 10.0f        // 1/0.1
#define NS_AGG 8             // n-slices (128 tokens each)
#define LOG_A (-4.17438727f) // -log(65)
#define LOG_B (-6.93147181f) // -log(1024)

typedef __attribute__((ext_vector_type(8))) short short8;
typedef __attribute__((ext_vector_type(4))) float floatx4;

typedef __attribute__((address_space(3))) unsigned int lds_uint;
typedef const __attribute__((address_space(1))) unsigned int glb_uint;

__device__ __forceinline__ void gload_lds16(const void* g, void* l) {
    __builtin_amdgcn_global_load_lds((glb_uint*)g, (lds_uint*)l, 16, 0, 0);
}

__device__ __forceinline__ unsigned short bf16_rne(float f) {
    unsigned u = __builtin_bit_cast(unsigned, f);
    unsigned r = u + 0x7FFFu + ((u >> 16) & 1u);
    return (unsigned short)(r >> 16);
}

__device__ __forceinline__ short8 cvt8(float4 a, float4 b) {
    short8 r;
    r[0] = (short)bf16_rne(a.x); r[1] = (short)bf16_rne(a.y);
    r[2] = (short)bf16_rne(a.z); r[3] = (short)bf16_rne(a.w);
    r[4] = (short)bf16_rne(b.x); r[5] = (short)bf16_rne(b.y);
    r[6] = (short)bf16_rne(b.z); r[7] = (short)bf16_rne(b.w);
    return r;
}

// ---------------- prep: pack W (blocks 0..575) + t-GEMM (blocks 576..671) --
__global__ __launch_bounds__(256) void prep(
    const float* __restrict__ Wf, const float* __restrict__ Ws,
    const float* __restrict__ bf, const float* __restrict__ bs,
    const float* __restrict__ x, const float* __restrict__ Wt,
    short* __restrict__ W_pack, float* __restrict__ bias_all,
    float* __restrict__ tpart)
{
    __shared__ float xr[256];
    const int blk = blockIdx.x, tid = threadIdx.x;
    if (blk < 576) {
        int idx = blk * 256 + tid;   // < 147456 exactly
        int g    = idx / 6144;
        int rem  = idx - g * 6144;
        int nf   = rem >> 9;
        int rem2 = rem & 511;
        int lane = rem2 >> 3;
        int j    = rem2 & 7;
        int k = g * 32 + (lane >> 4) * 8 + j;
        int c = nf * 16 + (lane & 15);
        float v = (c < CDIM) ? Wf[(size_t)k * CDIM + c] : Ws[(size_t)k * KDIM + (c - CDIM)];
        W_pack[idx] = (short)bf16_rne(v);
        if (idx < 192) bias_all[idx] = (idx < CDIM) ? bf[idx] : bs[idx - CDIM];
    } else {
        int i = blk - 576;           // 0..95
        int b = i / 3, dy = i - b * 3;
        xr[tid] = x[(size_t)b * NTOK * DIM + (size_t)dy * 256 + tid];
        __syncthreads();
        float acc = 0.f;
        const float* wp = Wt + (size_t)dy * 256 * TDIM + tid;
#pragma unroll 8
        for (int d = 0; d < 256; ++d) acc = fmaf(xr[d], wp[(size_t)d * TDIM], acc);
        tpart[((size_t)dy * BATCH + b) * TDIM + tid] = acc;
    }
}

// ---------------- fused f / s GEMM via MFMA + LDS staging ----------------
__global__ __launch_bounds__(256, 2) void gemm_fs(
    const float* __restrict__ x, const short* __restrict__ W_pack,
    const float* __restrict__ bias_all, const float* __restrict__ sharp_p,
    unsigned short* __restrict__ fT, float* __restrict__ Mmat)
{
    __shared__ __align__(16) short Bs[12288];  // 24 KB  [kk][nf][lane][8]
    __shared__ __align__(16) short As[4096];   //  8 KB  [wave][kk][lane][8]
    const int tid  = threadIdx.x;
    const int wave = tid >> 6, lane = tid & 63;
    const int quad = lane >> 4, lrow = lane & 15;
    const int R = blockIdx.x * 64 + wave * 16;

    const int arow = blockIdx.x * 64 + (tid >> 2);
    const float* asrc = x + ((size_t)(arow >> 10) * NTOK + 1 + (arow & 1023)) * DIM + (tid & 3) * 16;
    const int r    = (tid >> 2) & 15;
    const int seg  = tid & 3;
    const int kk_w = seg >> 1;
    const int q0   = (seg & 1) * 2;
    short* adst0 = &As[(((tid >> 6) * 2 + kk_w) * 64 + q0 * 16 + r) * 8];
    short* adst1 = &As[(((tid >> 6) * 2 + kk_w) * 64 + (q0 + 1) * 16 + r) * 8];

    floatx4 acc[12];
#pragma unroll
    for (int nf = 0; nf < 12; ++nf) acc[nf] = (floatx4){0.f, 0.f, 0.f, 0.f};

    float4 g0 = *(const float4*)(asrc);
    float4 g1 = *(const float4*)(asrc + 4);
    float4 g2 = *(const float4*)(asrc + 8);
    float4 g3 = *(const float4*)(asrc + 12);

    for (int ko = 0; ko < 12; ++ko) {
        __syncthreads();
        const short* bsrc = W_pack + ko * 12288 + tid * 8;
#pragma unroll
        for (int i = 0; i < 6; ++i)
            gload_lds16(bsrc + i * 2048, &Bs[i * 2048 + tid * 8]);
        *(short8*)adst0 = cvt8(g0, g1);
        *(short8*)adst1 = cvt8(g2, g3);
        if (ko < 11) {
            const float* ap = asrc + (ko + 1) * 64;
            g0 = *(const float4*)(ap);
            g1 = *(const float4*)(ap + 4);
            g2 = *(const float4*)(ap + 8);
            g3 = *(const float4*)(ap + 12);
        }
        __syncthreads();
#pragma unroll
        for (int kk = 0; kk < 2; ++kk) {
            short8 af = *(const short8*)&As[((wave * 2 + kk) * 64 + lane) * 8];
#pragma unroll
            for (int nf = 0; nf < 12; ++nf) {
                short8 bf8 = *(const short8*)&Bs[((kk * 12 + nf) * 64 + lane) * 8];
                acc[nf] = __builtin_amdgcn_mfma_f32_16x16x32_bf16(af, bf8, acc[nf], 0, 0, 0);
            }
        }
    }

    const float sc = sharp_p[0] * INV_REG;
    const int bb = R >> 10;
    const int tok = (R & 1023) + quad * 4;
#pragma unroll
    for (int nf = 0; nf < 12; ++nf) {
        const int c = nf * 16 + lrow;
        const float bias = bias_all[c];
        if (nf < 8) {
            ushort4 w;
            w.x = bf16_rne(acc[nf][0] + bias);
            w.y = bf16_rne(acc[nf][1] + bias);
            w.z = bf16_rne(acc[nf][2] + bias);
            w.w = bf16_rne(acc[nf][3] + bias);
            *(ushort4*)(fT + ((size_t)bb * CDIM + c) * NM1 + tok) = w;
        } else {
            const int k = c - CDIM;
            float4 w = make_float4((acc[nf][0] + bias) * sc, (acc[nf][1] + bias) * sc,
                                   (acc[nf][2] + bias) * sc, (acc[nf][3] + bias) * sc);
            *(float4*)(Mmat + ((size_t)bb * KDIM + k) * NM1 + tok) = w;
        }
    }
}

// ---------------- sinkhorn u0: one wave per (b,k) row, v = 0 ---------------
__global__ __launch_bounds__(256) void sink_u0(
    const float* __restrict__ Mmat, const float* __restrict__ dust_p,
    float* __restrict__ u_out)
{
    const int wv   = (blockIdx.x << 2) + (threadIdx.x >> 6);
    const int lane = threadIdx.x & 63;
    const int b = wv / 65, k = wv - b * 65;
    const float dustM = dust_p[0] * INV_REG;

    if (k == 64) {   // dust row: all entries == dustM
        if (lane == 0) u_out[wv] = LOG_A - (dustM + 6.93147181f);  // log(1024)
        return;
    }
    const float4* Mp = (const float4*)(Mmat + ((size_t)b * KDIM + k) * NM1);
    float xs[16];
#pragma unroll
    for (int i = 0; i < 4; ++i) {
        float4 mv = Mp[i * 64 + lane];
        xs[i * 4 + 0] = mv.x; xs[i * 4 + 1] = mv.y;
        xs[i * 4 + 2] = mv.z; xs[i * 4 + 3] = mv.w;
    }
    float m = xs[0];
#pragma unroll
    for (int i = 1; i < 16; ++i) m = fmaxf(m, xs[i]);
#pragma unroll
    for (int off = 1; off < 64; off <<= 1) m = fmaxf(m, __shfl_xor(m, off));
    float S = 0.f;
#pragma unroll
    for (int i = 0; i < 16; ++i) S += __expf(xs[i] - m);
#pragma unroll
    for (int off = 1; off < 64; off <<= 1) S += __shfl_xor(S, off);
    if (lane == 0) u_out[wv] = LOG_A - (m + __logf(S));
}

// ---------------- sink_step: merge-u -> v-update -> (partials | aggregate) -
// grid (BATCH, NS_AGG) x 256. Block owns M[b][all k][ns*128 .. +127] in LDS.
// FIRST: u comes complete from u_in (sink_u0). Else: merge 8 slice partials
// (written by previous dispatch) from u_in.
// LAST: fuse the MFMA aggregation (p A-frags in-register, fT B-frags).
template<bool FIRST, bool LAST>
__global__ __launch_bounds__(256) void sink_step(
    const float* __restrict__ Mmat, const float* __restrict__ dust_p,
    const float* __restrict__ u_in, float* __restrict__ up_out,
    const unsigned short* __restrict__ fT,
    float* __restrict__ vpart, float* __restrict__ rspart)
{
    __shared__ float Msh[KDIM * 128];   // 32 KB
    __shared__ float us[65];
    __shared__ float vs[128];
    const int b = blockIdx.x, ns = blockIdx.y;
    const int tid = threadIdx.x;
    const int wave = tid >> 6, lane = tid & 63;
    const float dustM = dust_p[0] * INV_REG;

    // stage M slice (64 rows x 128 cols)
    const float* msrc = Mmat + (size_t)b * KDIM * NM1 + ns * 128;
#pragma unroll
    for (int q = 0; q < 8; ++q) {
        int idx = q * 256 + tid;
        int k = idx >> 5, j4 = idx & 31;
        *(float4*)&Msh[k * 128 + j4 * 4] = *(const float4*)(msrc + (size_t)k * NM1 + j4 * 4);
    }

    // phase A: u
    if (tid < 65) {
        if (FIRST) {
            us[tid] = u_in[b * 65 + tid];
        } else {
            const float* pp = u_in + b * 1040 + tid * 16;
            float m = pp[0], S = pp[1];
#pragma unroll
            for (int j = 1; j < 8; ++j) {
                float m2 = pp[j * 2], S2 = pp[j * 2 + 1];
                float nm = fmaxf(m, m2);
                S = S * __expf(m - nm) + S2 * __expf(m2 - nm);
                m = nm;
            }
            us[tid] = LOG_A - (m + __logf(S));
        }
    }
    __syncthreads();

    // phase B: v-update for the block's 128 columns
    if (tid < 128) {
        float xs[64];
#pragma unroll
        for (int k = 0; k < 64; ++k) xs[k] = Msh[k * 128 + tid] + us[k];
        const float xd = dustM + us[64];
        float m = xd;
#pragma unroll
        for (int k = 0; k < 64; ++k) m = fmaxf(m, xs[k]);
        float S = __expf(xd - m);
#pragma unroll
        for (int k = 0; k < 64; ++k) S += __expf(xs[k] - m);
        vs[tid] = LOG_B - (m + __logf(S));
    }
    __syncthreads();

    if (!LAST) {
        // phase C: (max,S) u-partials over these 128 columns, next iter
#pragma unroll 4
        for (int r = 0; r < 16; ++r) {
            const int k = wave * 16 + r;
            float x0 = Msh[k * 128 + lane] + vs[lane];
            float x1 = Msh[k * 128 + 64 + lane] + vs[64 + lane];
            float m = fmaxf(x0, x1);
#pragma unroll
            for (int off = 1; off < 64; off <<= 1) m = fmaxf(m, __shfl_xor(m, off));
            float S = __expf(x0 - m) + __expf(x1 - m);
#pragma unroll
            for (int off = 1; off < 64; off <<= 1) S += __shfl_xor(S, off);
            if (lane == 0)
                *(float2*)&up_out[b * 1040 + k * 16 + ns * 2] = make_float2(m, S);
        }
        if (wave == 0) {   // dust row k=64
            float x0 = dustM + vs[lane];
            float x1 = dustM + vs[64 + lane];
            float m = fmaxf(x0, x1);
#pragma unroll
            for (int off = 1; off < 64; off <<= 1) m = fmaxf(m, __shfl_xor(m, off));
            float S = __expf(x0 - m) + __expf(x1 - m);
#pragma unroll
            for (int off = 1; off < 64; off <<= 1) S += __shfl_xor(S, off);
            if (lane == 0)
                *(float2*)&up_out[b * 1040 + 64 * 16 + ns * 2] = make_float2(m, S);
        }
    } else {
        // fused aggregation: p = exp(M+u+v) as A-frags, fT as B-frags
        const int quad = lane >> 4, lrow = lane & 15;
        const int krow = wave * 16 + lrow;
        const float uk = us[krow];
        const float* Mrow = Mmat + ((size_t)b * KDIM + krow) * NM1 + ns * 128 + quad * 8;
        const unsigned short* fbase = fT + ((size_t)b * CDIM + lrow) * NM1 + ns * 128 + quad * 8;

        floatx4 acc[8];
#pragma unroll
        for (int nf = 0; nf < 8; ++nf) acc[nf] = (floatx4){0.f, 0.f, 0.f, 0.f};
        float rs = 0.f;

#pragma unroll
        for (int step = 0; step < 4; ++step) {
            const float* mp = Mrow + step * 32;
            float4 m0 = *(const float4*)(mp);
            float4 m1 = *(const float4*)(mp + 4);
            const int tb = step * 32 + quad * 8;
            float p[8];
            p[0] = __expf(m0.x + uk + vs[tb + 0]);
            p[1] = __expf(m0.y + uk + vs[tb + 1]);
            p[2] = __expf(m0.z + uk + vs[tb + 2]);
            p[3] = __expf(m0.w + uk + vs[tb + 3]);
            p[4] = __expf(m1.x + uk + vs[tb + 4]);
            p[5] = __expf(m1.y + uk + vs[tb + 5]);
            p[6] = __expf(m1.z + uk + vs[tb + 6]);
            p[7] = __expf(m1.w + uk + vs[tb + 7]);
            short8 afrag;
#pragma unroll
            for (int j = 0; j < 8; ++j) {
                rs += p[j];
                afrag[j] = (short)bf16_rne(p[j]);
            }
#pragma unroll
            for (int nf = 0; nf < 8; ++nf) {
                short8 bfrag = *(const short8*)(fbase + (size_t)nf * 16 * NM1 + step * 32);
                acc[nf] = __builtin_amdgcn_mfma_f32_16x16x32_bf16(afrag, bfrag, acc[nf], 0, 0, 0);
            }
        }

        rs += __shfl_xor(rs, 16);
        rs += __shfl_xor(rs, 32);
        if (lane < 16) rspart[(ns * BATCH + b) * KDIM + krow] = rs;

        float* vp = vpart + (size_t)(ns * BATCH + b) * (KDIM * CDIM);
#pragma unroll
        for (int nf = 0; nf < 8; ++nf) {
            const int c = nf * 16 + lrow;
#pragma unroll
            for (int j = 0; j < 4; ++j)
                vp[(size_t)(wave * 16 + quad * 4 + j) * CDIM + c] = acc[nf][j];
        }
    }
}

// ---------------- finalize: reduce partials, anchors, L2-normalize ---------
__global__ __launch_bounds__(1024) void finalize_all(
    const float* __restrict__ vpart, const float* __restrict__ rspart,
    const float* __restrict__ anchors, const float* __restrict__ tpart,
    const float* __restrict__ bt, float* __restrict__ out)
{
    __shared__ float rstot[KDIM];
    __shared__ float red[16];
    __shared__ float sc_sh;
    const int b = blockIdx.x, tid = threadIdx.x;
    const int lane = tid & 63, wave = tid >> 6;

    if (tid < KDIM) {
        float s = 0.f;
#pragma unroll
        for (int ns = 0; ns < NS_AGG; ++ns)
            s += rspart[(ns * BATCH + b) * KDIM + tid];
        rstot[tid] = s;
    }
    __syncthreads();

    const size_t e0 = (size_t)tid * 8;
    float4 s0 = make_float4(0.f, 0.f, 0.f, 0.f);
    float4 s1 = make_float4(0.f, 0.f, 0.f, 0.f);
#pragma unroll
    for (int ns = 0; ns < NS_AGG; ++ns) {
        const float* vp = vpart + (size_t)(ns * BATCH + b) * (KDIM * CDIM) + e0;
        float4 a = *(const float4*)(vp);
        float4 c = *(const float4*)(vp + 4);
        s0.x += a.x; s0.y += a.y; s0.z += a.z; s0.w += a.w;
        s1.x += c.x; s1.y += c.y; s1.z += c.z; s1.w += c.w;
    }
    const float rsv = rstot[tid >> 4];
    float4 a0 = *(const float4*)(anchors + e0);
    float4 a1 = *(const float4*)(anchors + e0 + 4);
    float4 v0, v1;
    v0.x = 2.f * s0.x - rsv * a0.x;  v0.y = 2.f * s0.y - rsv * a0.y;
    v0.z = 2.f * s0.z - rsv * a0.z;  v0.w = 2.f * s0.w - rsv * a0.w;
    v1.x = 2.f * s1.x - rsv * a1.x;  v1.y = 2.f * s1.y - rsv * a1.y;
    v1.z = 2.f * s1.z - rsv * a1.z;  v1.w = 2.f * s1.w - rsv * a1.w;
    float ss = v0.x*v0.x + v0.y*v0.y + v0.z*v0.z + v0.w*v0.w
             + v1.x*v1.x + v1.y*v1.y + v1.z*v1.z + v1.w*v1.w;

    float t = 0.f;
    if (tid < TDIM) {
        t = bt[tid];
#pragma unroll
        for (int s = 0; s < 3; ++s) t += tpart[((size_t)s * BATCH + b) * TDIM + tid];
        ss += t * t;
    }

#pragma unroll
    for (int off = 32; off > 0; off >>= 1) ss += __shfl_down(ss, off);
    if (lane == 0) red[wave] = ss;
    __syncthreads();
    if (tid == 0) {
        float tot = 0.f;
#pragma unroll
        for (int i = 0; i < 16; ++i) tot += red[i];
        sc_sh = 1.f / fmaxf(sqrtf(tot), 1e-12f);
    }
    __syncthreads();
    const float scale = sc_sh;

    float* orow = out + (size_t)b * ROWLEN;
    if (tid < TDIM) orow[tid] = t * scale;
    v0.x *= scale; v0.y *= scale; v0.z *= scale; v0.w *= scale;
    v1.x *= scale; v1.y *= scale; v1.z *= scale; v1.w *= scale;
    *(float4*)&orow[TDIM + e0]     = v0;
    *(float4*)&orow[TDIM + e0 + 4] = v1;
}

// ---------------- launcher ----------------
extern "C" void kernel_launch(void* const* d_in, const int* in_sizes, int n_in,
                              void* d_out, int out_size, void* d_ws, size_t ws_size,
                              hipStream_t stream)
{
    const float* x       = (const float*)d_in[0];
    const float* Wf      = (const float*)d_in[1];
    const float* bf      = (const float*)d_in[2];
    const float* Ws      = (const float*)d_in[3];
    const float* bs      = (const float*)d_in[4];
    const float* Wt      = (const float*)d_in[5];
    const float* bt      = (const float*)d_in[6];
    const float* anchors = (const float*)d_in[7];
    const float* dust    = (const float*)d_in[8];
    const float* sharp   = (const float*)d_in[9];
    float* out = (float*)d_out;

    char* base = (char*)d_ws;
    short* W_pack        = (short*)base;                       // 294912 B
    float* bias_all      = (float*)(base + 294912);            // 192 fl
    float* Mmat          = bias_all + 192;                     // 2097152 fl
    unsigned short* fT   = (unsigned short*)(Mmat + (size_t)BATCH * KDIM * NM1); // 4194304 us
    float* u_buf         = (float*)(fT + (size_t)BATCH * CDIM * NM1);  // 2080 fl
    float* upA           = u_buf + BATCH * 65;                 // 32*1040 fl
    float* upB           = upA + BATCH * 1040;                 // 32*1040 fl
    float* vpart         = upB + BATCH * 1040;                 // 2097152 fl
    float* rspart        = vpart + (size_t)NS_AGG * BATCH * KDIM * CDIM; // 16384 fl
    float* tpart         = rspart + NS_AGG * BATCH * KDIM;     // 24576 fl

    hipLaunchKernelGGL(prep, dim3(672), dim3(256), 0, stream,
                       Wf, Ws, bf, bs, x, Wt, W_pack, bias_all, tpart);
    hipLaunchKernelGGL(gemm_fs, dim3(512), dim3(256), 0, stream,
                       x, W_pack, bias_all, sharp, fT, Mmat);

    hipLaunchKernelGGL(sink_u0, dim3(520), dim3(256), 0, stream,
                       Mmat, dust, u_buf);
    // 5 iterations: F1 (reads full u1, writes P(u2)) ... F5 (merge u5, v5, agg)
    hipLaunchKernelGGL(HIP_KERNEL_NAME(sink_step<true,  false>), dim3(BATCH, NS_AGG), dim3(256), 0, stream,
                       Mmat, dust, u_buf, upA, fT, vpart, rspart);
    hipLaunchKernelGGL(HIP_KERNEL_NAME(sink_step<false, false>), dim3(BATCH, NS_AGG), dim3(256), 0, stream,
                       Mmat, dust, upA, upB, fT, vpart, rspart);
    hipLaunchKernelGGL(HIP_KERNEL_NAME(sink_step<false, false>), dim3(BATCH, NS_AGG), dim3(256), 0, stream,
                       Mmat, dust, upB, upA, fT, vpart, rspart);
    hipLaunchKernelGGL(HIP_KERNEL_NAME(sink_step<false, false>), dim3(BATCH, NS_AGG), dim3(256), 0, stream,
                       Mmat, dust, upA, upB, fT, vpart, rspart);
    hipLaunchKernelGGL(HIP_KERNEL_NAME(sink_step<false, true >), dim3(BATCH, NS_AGG), dim3(256), 0, stream,
                       Mmat, dust, upB, upA, fT, vpart, rspart);

    hipLaunchKernelGGL(finalize_all, dim3(BATCH), dim3(1024), 0, stream,
                       vpart, rspart, anchors, tpart, bt, out);
}